// Round 5
// baseline (712.960 us; speedup 1.0000x reference)
//
#include <hip/hip_runtime.h>
#include <hip/hip_bf16.h>

// DifferenceOfGaussians on MI355X — round 5.
// ONE fused kernel (hpass -> vdog -> detect -> emit) with custom device-scope
// grid barriers (all 896 blocks co-resident by construction). rowbits live in
// LDS across the detect->emit barrier. One hipMemsetAsync zeroes the barrier
// counters each launch.
//
// Workspace (bytes):
//   OFF_H    : float h[14][640][512]   (rows 43..554 data, 0..42 & 555..597
//              zero guards, 598..639 read-but-multiplied-by-zero)
//   OFF_DOG  : float dog[13][512][512]
//   OFF_GCNT : int   gcnt[832]
//   OFF_BAR  : int   bar[4]            (memset to 0 every launch)

#define OFF_H    0
#define OFF_DOG  18350080
#define OFF_GCNT 31981568
#define OFF_BAR  31985152

#define HROWS 640
#define HPAD  43
#define MAXPEAKS 32768
#define NBLK 896

// Normalized (optionally sign-flipped) weights, zero-padded to 96, one wave.
// Matches reference exp(-(d/(2s))^2) / sum.
__device__ __forceinline__ void make_w(float s, double sgn, double* wl, int lane) {
    int r = (int)(4.0f * s + 0.5f);
    int n = 2 * r + 1;
    double v0 = 0.0, v1 = 0.0;
    double sd = (double)s;
    if (lane < n) {
        double d = (double)(lane - r), q = d / (2.0 * sd);
        v0 = exp(-q * q);
    }
    if (lane + 64 < n) {
        double d = (double)(lane + 64 - r), q = d / (2.0 * sd);
        v1 = exp(-q * q);
    }
    double part = v0 + v1;
    for (int m = 1; m < 64; m <<= 1) part += __shfl_xor(part, m);
    double inv = sgn / part;
    wl[lane] = v0 * inv;
    if (lane + 64 < 96) wl[lane + 64] = v1 * inv;
}

// Unconditional guarded vertical conv: bp points at padded row (y0 - r + HPAD).
__device__ __forceinline__ void conv_acc(const float* __restrict__ bp,
                                         int nceil, const double* __restrict__ wl,
                                         double (&acc)[16]) {
    double win[16];
#pragma unroll
    for (int sl = 0; sl < 16; ++sl) win[sl] = (double)bp[sl * 512];
    for (int dc = 0; dc < nceil; dc += 16) {
        const float* rp = bp + (dc + 16) * 512;
#pragma unroll
        for (int k = 0; k < 16; ++k) {
            double wd = wl[dc + k];
#pragma unroll
            for (int j = 0; j < 16; ++j)
                acc[j] = fma(wd, win[(k + j) & 15], acc[j]);
            win[k] = (double)rp[k * 512];
        }
    }
}

__device__ __forceinline__ void gridbar(int* c) {
    __syncthreads();
    if (threadIdx.x == 0) {
        __threadfence();                                  // release our writes
        __hip_atomic_fetch_add(c, 1, __ATOMIC_RELEASE, __HIP_MEMORY_SCOPE_AGENT);
        while (__hip_atomic_load(c, __ATOMIC_ACQUIRE, __HIP_MEMORY_SCOPE_AGENT) < NBLK)
            __builtin_amdgcn_s_sleep(1);
        __threadfence();                                  // acquire others'
    }
    __syncthreads();
}

__global__ __launch_bounds__(256, 4)
void dog_fused(const float* __restrict__ x, const float* __restrict__ sigma_list,
               float* __restrict__ h, float* __restrict__ dog,
               int* __restrict__ gcnt, int* __restrict__ bar,
               float* __restrict__ out) {
    __shared__ double s_wl[4][2][96];          // 6144 B (per-wave vdog weights)
    __shared__ float  s_buf[8][648];           // 20736 B (hpass rows / detect cml)
    __shared__ unsigned long long s_m[64];     // rowbits, detect -> emit
    __shared__ int s_cnt[8][8];
    __shared__ int s_redA[256], s_redB[256];
    __shared__ int s_pre[64];

    const int t = threadIdx.x;
    const int b = blockIdx.x;
    const int lane = t & 63;
    const int wv = t >> 6;

    // ================= phase 1: horizontal blur (job = block) =================
    {
        const int plane = 13 - (b >> 6);       // heavy plane first
        const int rg = b & 63;
        float s = sigma_list[plane];
        int r = (int)(4.0f * s + 0.5f);
        int n = 2 * r + 1;
        int nceil = (n + 15) & ~15;
        double* wl = &s_wl[0][0][0];
        if (t < 64) make_w(s, +1.0, wl, t);

        // zero this block's share of the 86 guard rows of its plane
        float* hp0 = h + plane * (HROWS * 512);
        for (int k = t; k < 688; k += 256) {
            int f = rg * 688 + k;              // 0..44031 = 86*512
            int g = f >> 9, xc = f & 511;
            int row = (g < HPAD) ? g : (g + 512);
            hp0[row * 512 + xc] = 0.0f;
        }
        // stage 8 zero-padded rows, skewed (addr = p + p/16)
        int y8 = rg * 8;
        for (int rr = 0; rr < 8; ++rr)
            for (int k = t; k < 608; k += 256) {
                int gx = k - 43;
                float val = ((unsigned)gx < 512u) ? x[(y8 + rr) * 512 + gx] : 0.0f;
                s_buf[rr][k + (k >> 4)] = val;
            }
        __syncthreads();

        int tsub = t & 31, row = t >> 5;
        int xb = tsub * 16;
        int P0 = 43 - r + xb;
        double acc[16], win[16];
#pragma unroll
        for (int j = 0; j < 16; ++j) acc[j] = 0.0;
#pragma unroll
        for (int sl = 0; sl < 16; ++sl) {
            int p = P0 + sl;
            win[sl] = (double)s_buf[row][p + (p >> 4)];
        }
        for (int dc = 0; dc < nceil; dc += 16) {
#pragma unroll
            for (int k = 0; k < 16; ++k) {
                double wd = wl[dc + k];
#pragma unroll
                for (int j = 0; j < 16; ++j)
                    acc[j] = fma(wd, win[(k + j) & 15], acc[j]);
                int p = P0 + dc + k + 16;
                win[k] = (double)s_buf[row][p + (p >> 4)];
            }
        }
        float* hp = h + (plane * HROWS + HPAD + y8 + row) * 512 + xb;
#pragma unroll
        for (int j = 0; j < 16; ++j) hp[j] = (float)acc[j];
    }
    gridbar(&bar[0]);

    // ============ phase 2: vertical blur pair + DoG (job = wave) ==============
    {
        int gw = b * 4 + wv;                   // 0..3583; 3328 jobs, heavy first
        if (gw < 3328) {
            int di = 12 - (gw >> 8);
            int rem = gw & 255;
            int xx = (rem & 7) * 64 + lane;
            int y0 = (rem >> 3) * 16;
            float s0 = sigma_list[di], s1 = sigma_list[di + 1];
            int r0 = (int)(4.0f * s0 + 0.5f), nc0 = (2 * r0 + 16) & ~15;
            int r1 = (int)(4.0f * s1 + 0.5f), nc1 = (2 * r1 + 16) & ~15;
            double* wl0 = &s_wl[wv][0][0];
            double* wl1 = &s_wl[wv][1][0];
            make_w(s0, +1.0, wl0, lane);
            make_w(s1, -1.0, wl1, lane);       // negated: acc = conv0 - conv1
            double acc[16];
#pragma unroll
            for (int j = 0; j < 16; ++j) acc[j] = 0.0;
            const float* hp0 = h + di * (HROWS * 512);
            conv_acc(hp0 + (HPAD + y0 - r0) * 512 + xx, nc0, wl0, acc);
            conv_acc(hp0 + HROWS * 512 + (HPAD + y0 - r1) * 512 + xx, nc1, wl1, acc);
            double sg = (double)s0;
            float* dp = dog + (di * 512 + y0) * 512 + xx;
#pragma unroll
            for (int j = 0; j < 16; ++j) dp[j * 512] = (float)(acc[j] * sg);
        }
    }
    gridbar(&bar[1]);

    // ============ phase 3: 3x3x3 peak detect (832 block-jobs) =================
    if (b < 832) {
        const int s = b >> 6;
        const int y0 = (b & 63) * 8;
        if (s == 0 || s == 12) {
            if (t < 64) s_m[t] = 0ull;
            if (t == 0) gcnt[b] = 0;
        } else {
            float vcen[2][8];
#pragma unroll
            for (int half = 0; half < 2; ++half) {
                int xx = half * 256 + t;
                float pm[10];
#pragma unroll
                for (int q = 0; q < 10; ++q) {
                    int yy = y0 - 1 + q;
                    float m = -3.0e38f;
                    if ((unsigned)yy < 512u) {
                        float a  = dog[((s - 1) * 512 + yy) * 512 + xx];
                        float bb = dog[(s * 512 + yy) * 512 + xx];
                        float c  = dog[((s + 1) * 512 + yy) * 512 + xx];
                        m = fmaxf(a, fmaxf(bb, c));
                        if (q >= 1 && q <= 8) vcen[half][q - 1] = bb;
                    } else if (q >= 1 && q <= 8) vcen[half][q - 1] = 0.0f;
                    pm[q] = m;
                }
#pragma unroll
                for (int k = 0; k < 8; ++k)
                    s_buf[k][xx] = fmaxf(pm[k], fmaxf(pm[k + 1], pm[k + 2]));
            }
            __syncthreads();
#pragma unroll
            for (int k = 0; k < 8; ++k) {
                int y = y0 + k;
#pragma unroll
                for (int half = 0; half < 2; ++half) {
                    int xx = half * 256 + t;
                    bool peak = false;
                    if (xx >= 1 && xx <= 510 && y >= 1 && y <= 510) {
                        float v = vcen[half][k];
                        if (v > 0.001f) {
                            float mx = fmaxf(s_buf[k][xx - 1],
                                       fmaxf(s_buf[k][xx], s_buf[k][xx + 1]));
                            peak = (v >= mx);  // mx includes v
                        }
                    }
                    unsigned long long mm = __ballot(peak);
                    int word = half * 4 + wv;
                    if (lane == 0) {
                        s_m[k * 8 + word] = mm;
                        s_cnt[k][word] = __popcll(mm);
                    }
                }
            }
            __syncthreads();
            if (t == 0) {
                int c = 0;
#pragma unroll
                for (int k = 0; k < 8; ++k)
#pragma unroll
                    for (int q = 0; q < 8; ++q) c += s_cnt[k][q];
                gcnt[b] = c;
            }
        }
    }
    gridbar(&bar[2]);

    // ============ phase 4: ordered emit + padding fill ========================
    {
        int pa = 0, pb = 0;
#pragma unroll
        for (int jj = 0; jj < 4; ++jj) {
            int idx = t + jj * 256;
            if (idx < 832) {
                int c = gcnt[idx];
                pb += c;
                if (idx < b) pa += c;
            }
        }
        s_redA[t] = pa;
        s_redB[t] = pb;
        __syncthreads();
        for (int off = 128; off > 0; off >>= 1) {
            if (t < off) { s_redA[t] += s_redA[t + off]; s_redB[t] += s_redB[t + off]; }
            __syncthreads();
        }
        int gbase = s_redA[0];
        int tot = min(s_redB[0], MAXPEAKS);
        __syncthreads();

        if (b < 832 && (b >> 6) != 0 && (b >> 6) != 12) {
            if (t < 64) {                      // wave-0 scan of word counts
                int wc = (int)__popcll(s_m[t]);
                int inc = wc;
                for (int off = 1; off < 64; off <<= 1) {
                    int v = __shfl_up(inc, off);
                    if (lane >= off) inc += v;
                }
                s_pre[t] = inc - wc;
            }
            __syncthreads();
            const int s = b >> 6;
            const int y0 = (b & 63) * 8;
            float sg = sigma_list[s];
#pragma unroll
            for (int k = 0; k < 8; ++k)
#pragma unroll
                for (int half = 0; half < 2; ++half) {
                    int word = half * 4 + wv;
                    unsigned long long mw = s_m[k * 8 + word];
                    if ((mw >> lane) & 1ull) {
                        int pos = gbase + s_pre[k * 8 + word]
                                + (int)__popcll(mw & ((1ull << lane) - 1ull));
                        if (pos < MAXPEAKS) {
                            out[pos * 3 + 0] = sg;
                            out[pos * 3 + 1] = (float)(y0 + k);
                            out[pos * 3 + 2] = (float)(word * 64 + lane);
                        }
                    }
                }
        }
        int idx = b * 256 + t;                 // blocks 0..127 cover 32768 rows
        if (idx < MAXPEAKS && idx >= tot) {
            out[idx * 3 + 0] = sigma_list[0];
            out[idx * 3 + 1] = 0.0f;
            out[idx * 3 + 2] = 0.0f;
        }
    }
}

extern "C" void kernel_launch(void* const* d_in, const int* in_sizes, int n_in,
                              void* d_out, int out_size, void* d_ws, size_t ws_size,
                              hipStream_t stream) {
    const float* x     = (const float*)d_in[0];   // [1,1,512,512]
    const float* sigma = (const float*)d_in[2];   // [14]
    float* out = (float*)d_out;                   // [32768,3]

    char* ws = (char*)d_ws;
    float* h   = (float*)(ws + OFF_H);
    float* dog = (float*)(ws + OFF_DOG);
    int* gcnt  = (int*)(ws + OFF_GCNT);
    int* bar   = (int*)(ws + OFF_BAR);

    hipMemsetAsync(bar, 0, 16, stream);           // single-use barrier counters
    dog_fused<<<NBLK, 256, 0, stream>>>(x, sigma, h, dog, gcnt, bar, out);
}

// Round 6
// 414.620 us; speedup vs baseline: 1.7195x; 1.7195x over previous
//
#include <hip/hip_runtime.h>
#include <hip/hip_bf16.h>

// DifferenceOfGaussians on MI355X — round 6.
// ONE fused kernel with RELAXED-spin grid barriers (round-5's acquire-per-poll
// caused an L2-invalidate storm: 712us, VALUBusy 3%). Fences: exactly one
// release (wbL2) before arrive, one acquire (inv) after spin exit.
// Balanced job maps: phase1 plane = b%14, phase2 di = gw%13.
//
// Workspace (bytes):
//   OFF_H    : float h[14][640][512]   (rows 43..554 data, 0..42 & 555..597
//              zero guards, 598..639 read-but-multiplied-by-zero)
//   OFF_DOG  : float dog[13][512][512]
//   OFF_GCNT : int   gcnt[832]
//   OFF_BAR  : int   bar[4]            (memset to 0 every launch)

#define OFF_H    0
#define OFF_DOG  18350080
#define OFF_GCNT 31981568
#define OFF_BAR  31985152

#define HROWS 640
#define HPAD  43
#define MAXPEAKS 32768
#define NBLK 896

// Normalized (optionally sign-flipped) weights, zero-padded to 96, one wave.
// Matches reference exp(-(d/(2s))^2) / sum.
__device__ __forceinline__ void make_w(float s, double sgn, double* wl, int lane) {
    int r = (int)(4.0f * s + 0.5f);
    int n = 2 * r + 1;
    double v0 = 0.0, v1 = 0.0;
    double sd = (double)s;
    if (lane < n) {
        double d = (double)(lane - r), q = d / (2.0 * sd);
        v0 = exp(-q * q);
    }
    if (lane + 64 < n) {
        double d = (double)(lane + 64 - r), q = d / (2.0 * sd);
        v1 = exp(-q * q);
    }
    double part = v0 + v1;
    for (int m = 1; m < 64; m <<= 1) part += __shfl_xor(part, m);
    double inv = sgn / part;
    wl[lane] = v0 * inv;
    if (lane + 64 < 96) wl[lane + 64] = v1 * inv;
}

// Unconditional guarded vertical conv: bp points at padded row (y0 - r + HPAD).
__device__ __forceinline__ void conv_acc(const float* __restrict__ bp,
                                         int nceil, const double* __restrict__ wl,
                                         double (&acc)[16]) {
    double win[16];
#pragma unroll
    for (int sl = 0; sl < 16; ++sl) win[sl] = (double)bp[sl * 512];
    for (int dc = 0; dc < nceil; dc += 16) {
        const float* rp = bp + (dc + 16) * 512;
#pragma unroll
        for (int k = 0; k < 16; ++k) {
            double wd = wl[dc + k];
#pragma unroll
            for (int j = 0; j < 16; ++j)
                acc[j] = fma(wd, win[(k + j) & 15], acc[j]);
            win[k] = (double)rp[k * 512];
        }
    }
}

// Grid barrier: relaxed spin (atomic loads bypass non-coherent L2 but do NOT
// invalidate caches), one release fence before arrive, one acquire after exit.
__device__ __forceinline__ void gridbar(int* c) {
    __syncthreads();
    if (threadIdx.x == 0) {
        __builtin_amdgcn_fence(__ATOMIC_RELEASE, "agent");      // wb dirty L2
        __hip_atomic_fetch_add(c, 1, __ATOMIC_RELAXED, __HIP_MEMORY_SCOPE_AGENT);
        while (__hip_atomic_load(c, __ATOMIC_RELAXED, __HIP_MEMORY_SCOPE_AGENT) < NBLK)
            __builtin_amdgcn_s_sleep(8);
        __builtin_amdgcn_fence(__ATOMIC_ACQUIRE, "agent");      // one inv
    }
    __syncthreads();
}

__global__ __launch_bounds__(256, 4)
void dog_fused(const float* __restrict__ x, const float* __restrict__ sigma_list,
               float* __restrict__ h, float* __restrict__ dog,
               int* __restrict__ gcnt, int* __restrict__ bar,
               float* __restrict__ out) {
    __shared__ double s_wl[4][2][96];          // 6144 B (per-wave vdog weights)
    __shared__ float  s_buf[8][648];           // 20736 B (hpass rows / detect cml)
    __shared__ unsigned long long s_m[64];     // rowbits, detect -> emit
    __shared__ int s_cnt[8][8];
    __shared__ int s_redA[256], s_redB[256];
    __shared__ int s_pre[64];

    const int t = threadIdx.x;
    const int b = blockIdx.x;
    const int lane = t & 63;
    const int wv = t >> 6;

    // ================= phase 1: horizontal blur (job = block) =================
    {
        const int plane = b % 14;              // interleave planes across CUs
        const int rg = b / 14;                 // 0..63
        float s = sigma_list[plane];
        int r = (int)(4.0f * s + 0.5f);
        int n = 2 * r + 1;
        int nceil = (n + 15) & ~15;
        double* wl = &s_wl[0][0][0];
        if (t < 64) make_w(s, +1.0, wl, t);

        // zero this block's share of the 86 guard rows of its plane
        float* hp0 = h + plane * (HROWS * 512);
        for (int k = t; k < 688; k += 256) {
            int f = rg * 688 + k;              // 0..44031 = 86*512
            int g = f >> 9, xc = f & 511;
            int row = (g < HPAD) ? g : (g + 512);
            hp0[row * 512 + xc] = 0.0f;
        }
        // stage 8 zero-padded rows, skewed (addr = p + p/16)
        int y8 = rg * 8;
        for (int rr = 0; rr < 8; ++rr)
            for (int k = t; k < 608; k += 256) {
                int gx = k - 43;
                float val = ((unsigned)gx < 512u) ? x[(y8 + rr) * 512 + gx] : 0.0f;
                s_buf[rr][k + (k >> 4)] = val;
            }
        __syncthreads();

        int tsub = t & 31, row = t >> 5;
        int xb = tsub * 16;
        int P0 = 43 - r + xb;
        double acc[16], win[16];
#pragma unroll
        for (int j = 0; j < 16; ++j) acc[j] = 0.0;
#pragma unroll
        for (int sl = 0; sl < 16; ++sl) {
            int p = P0 + sl;
            win[sl] = (double)s_buf[row][p + (p >> 4)];
        }
        for (int dc = 0; dc < nceil; dc += 16) {
#pragma unroll
            for (int k = 0; k < 16; ++k) {
                double wd = wl[dc + k];
#pragma unroll
                for (int j = 0; j < 16; ++j)
                    acc[j] = fma(wd, win[(k + j) & 15], acc[j]);
                int p = P0 + dc + k + 16;
                win[k] = (double)s_buf[row][p + (p >> 4)];
            }
        }
        float* hp = h + (plane * HROWS + HPAD + y8 + row) * 512 + xb;
#pragma unroll
        for (int j = 0; j < 16; ++j) hp[j] = (float)acc[j];
    }
    gridbar(&bar[0]);

    // ============ phase 2: vertical blur pair + DoG (job = wave) ==============
    {
        int gw = b * 4 + wv;                   // 0..3583; 3328 jobs
        if (gw < 3328) {
            int di = gw % 13;                  // interleave pair weight across CUs
            int rem = gw / 13;                 // 0..255
            int xx = (rem & 7) * 64 + lane;
            int y0 = (rem >> 3) * 16;
            float s0 = sigma_list[di], s1 = sigma_list[di + 1];
            int r0 = (int)(4.0f * s0 + 0.5f), nc0 = (2 * r0 + 16) & ~15;
            int r1 = (int)(4.0f * s1 + 0.5f), nc1 = (2 * r1 + 16) & ~15;
            double* wl0 = &s_wl[wv][0][0];
            double* wl1 = &s_wl[wv][1][0];
            make_w(s0, +1.0, wl0, lane);
            make_w(s1, -1.0, wl1, lane);       // negated: acc = conv0 - conv1
            double acc[16];
#pragma unroll
            for (int j = 0; j < 16; ++j) acc[j] = 0.0;
            const float* hp0 = h + di * (HROWS * 512);
            conv_acc(hp0 + (HPAD + y0 - r0) * 512 + xx, nc0, wl0, acc);
            conv_acc(hp0 + HROWS * 512 + (HPAD + y0 - r1) * 512 + xx, nc1, wl1, acc);
            double sg = (double)s0;
            float* dp = dog + (di * 512 + y0) * 512 + xx;
#pragma unroll
            for (int j = 0; j < 16; ++j) dp[j * 512] = (float)(acc[j] * sg);
        }
    }
    gridbar(&bar[1]);

    // ============ phase 3: 3x3x3 peak detect (832 block-jobs) =================
    if (b < 832) {
        const int s = b >> 6;
        const int y0 = (b & 63) * 8;
        if (s == 0 || s == 12) {
            if (t < 64) s_m[t] = 0ull;
            if (t == 0) gcnt[b] = 0;
        } else {
            float vcen[2][8];
#pragma unroll
            for (int half = 0; half < 2; ++half) {
                int xx = half * 256 + t;
                float pm[10];
#pragma unroll
                for (int q = 0; q < 10; ++q) {
                    int yy = y0 - 1 + q;
                    float m = -3.0e38f;
                    if ((unsigned)yy < 512u) {
                        float a  = dog[((s - 1) * 512 + yy) * 512 + xx];
                        float bb = dog[(s * 512 + yy) * 512 + xx];
                        float c  = dog[((s + 1) * 512 + yy) * 512 + xx];
                        m = fmaxf(a, fmaxf(bb, c));
                        if (q >= 1 && q <= 8) vcen[half][q - 1] = bb;
                    } else if (q >= 1 && q <= 8) vcen[half][q - 1] = 0.0f;
                    pm[q] = m;
                }
#pragma unroll
                for (int k = 0; k < 8; ++k)
                    s_buf[k][xx] = fmaxf(pm[k], fmaxf(pm[k + 1], pm[k + 2]));
            }
            __syncthreads();
#pragma unroll
            for (int k = 0; k < 8; ++k) {
                int y = y0 + k;
#pragma unroll
                for (int half = 0; half < 2; ++half) {
                    int xx = half * 256 + t;
                    bool peak = false;
                    if (xx >= 1 && xx <= 510 && y >= 1 && y <= 510) {
                        float v = vcen[half][k];
                        if (v > 0.001f) {
                            float mx = fmaxf(s_buf[k][xx - 1],
                                       fmaxf(s_buf[k][xx], s_buf[k][xx + 1]));
                            peak = (v >= mx);  // mx includes v
                        }
                    }
                    unsigned long long mm = __ballot(peak);
                    int word = half * 4 + wv;
                    if (lane == 0) {
                        s_m[k * 8 + word] = mm;
                        s_cnt[k][word] = __popcll(mm);
                    }
                }
            }
            __syncthreads();
            if (t == 0) {
                int c = 0;
#pragma unroll
                for (int k = 0; k < 8; ++k)
#pragma unroll
                    for (int q = 0; q < 8; ++q) c += s_cnt[k][q];
                gcnt[b] = c;
            }
        }
    }
    gridbar(&bar[2]);

    // ============ phase 4: ordered emit + padding fill ========================
    {
        int pa = 0, pb = 0;
#pragma unroll
        for (int jj = 0; jj < 4; ++jj) {
            int idx = t + jj * 256;
            if (idx < 832) {
                int c = gcnt[idx];
                pb += c;
                if (idx < b) pa += c;
            }
        }
        s_redA[t] = pa;
        s_redB[t] = pb;
        __syncthreads();
        for (int off = 128; off > 0; off >>= 1) {
            if (t < off) { s_redA[t] += s_redA[t + off]; s_redB[t] += s_redB[t + off]; }
            __syncthreads();
        }
        int gbase = s_redA[0];
        int tot = min(s_redB[0], MAXPEAKS);
        __syncthreads();

        if (b < 832 && (b >> 6) != 0 && (b >> 6) != 12) {
            if (t < 64) {                      // wave-0 scan of word counts
                int wc = (int)__popcll(s_m[t]);
                int inc = wc;
                for (int off = 1; off < 64; off <<= 1) {
                    int v = __shfl_up(inc, off);
                    if (lane >= off) inc += v;
                }
                s_pre[t] = inc - wc;
            }
            __syncthreads();
            const int s = b >> 6;
            const int y0 = (b & 63) * 8;
            float sg = sigma_list[s];
#pragma unroll
            for (int k = 0; k < 8; ++k)
#pragma unroll
                for (int half = 0; half < 2; ++half) {
                    int word = half * 4 + wv;
                    unsigned long long mw = s_m[k * 8 + word];
                    if ((mw >> lane) & 1ull) {
                        int pos = gbase + s_pre[k * 8 + word]
                                + (int)__popcll(mw & ((1ull << lane) - 1ull));
                        if (pos < MAXPEAKS) {
                            out[pos * 3 + 0] = sg;
                            out[pos * 3 + 1] = (float)(y0 + k);
                            out[pos * 3 + 2] = (float)(word * 64 + lane);
                        }
                    }
                }
        }
        int idx = b * 256 + t;                 // blocks 0..127 cover 32768 rows
        if (idx < MAXPEAKS && idx >= tot) {
            out[idx * 3 + 0] = sigma_list[0];
            out[idx * 3 + 1] = 0.0f;
            out[idx * 3 + 2] = 0.0f;
        }
    }
}

extern "C" void kernel_launch(void* const* d_in, const int* in_sizes, int n_in,
                              void* d_out, int out_size, void* d_ws, size_t ws_size,
                              hipStream_t stream) {
    const float* x     = (const float*)d_in[0];   // [1,1,512,512]
    const float* sigma = (const float*)d_in[2];   // [14]
    float* out = (float*)d_out;                   // [32768,3]

    char* ws = (char*)d_ws;
    float* h   = (float*)(ws + OFF_H);
    float* dog = (float*)(ws + OFF_DOG);
    int* gcnt  = (int*)(ws + OFF_GCNT);
    int* bar   = (int*)(ws + OFF_BAR);

    hipMemsetAsync(bar, 0, 16, stream);           // single-use barrier counters
    dog_fused<<<NBLK, 256, 0, stream>>>(x, sigma, h, dog, gcnt, bar, out);
}

// Round 7
// 110.349 us; speedup vs baseline: 6.4609x; 3.7573x over previous
//
#include <hip/hip_runtime.h>
#include <hip/hip_bf16.h>

// DifferenceOfGaussians on MI355X — round 7: REVERT to the proven round-4
// four-kernel structure.
//
// Round 5/6 lesson (documented so it isn't retried): single fused kernel with
// device-scope software grid barriers costs ~100us PER BARRIER on gfx950
// regardless of fence discipline (acquire-per-poll spin: 712us; relaxed spin
// with single release/acquire fences: 414us; VALU-issue time in both ~20us).
// Each block's release fence = buffer_wbl2 and exit acquire = buffer_inv;
// ~900 blocks x 3 barriers serially thrash the non-coherent per-XCD L2s and
// repeatedly re-cold the caches for blocks already in the next phase.
// Kernel launches (~5-8us gaps) are strictly cheaper. Do not re-fuse.
//
// Structure: guard-padded h => unconditional vdog loads (pure fp64 FMA loop);
// no scan kernel (group counts + per-block redundant reduce in emit);
// 4 kernels: hpass, vdog, detect, emit. fp64 accumulation throughout
// (absmax 0.0 across three prior passing rounds — peak-set ordering is the
// real correctness risk; do not weaken numerics).
//
// Workspace (bytes):
//   OFF_H    : float h[14][640][512]   = 18,350,080  (rows 43..554 = data,
//              rows 0..42 & 555..597 zero guards, 598..639 read-but-zero-weight)
//   OFF_DOG  : float dog[13][512][512] = 13,631,488
//   OFF_BITS : u64  rowbits[6656][8]   =    425,984
//   OFF_GCNT : int  gcnt[832]          (peaks per 8-row group)
// total ~32.4 MB

#define OFF_H    0
#define OFF_DOG  18350080
#define OFF_BITS 31981568
#define OFF_GCNT 32407552

#define HROWS 640
#define HPAD  43
#define NSIG 13
#define MAXPEAKS 32768

// Build normalized (optionally sign-flipped) weights, zero-padded to 96,
// using one 64-lane wave. Matches reference exp(-(d/(2s))^2) / sum.
__device__ __forceinline__ void make_w(float s, double sgn, double* wl, int lane) {
    int r = (int)(4.0f * s + 0.5f);
    int n = 2 * r + 1;
    double v0 = 0.0, v1 = 0.0;
    double sd = (double)s;
    if (lane < n) {
        double d = (double)(lane - r), q = d / (2.0 * sd);
        v0 = exp(-q * q);
    }
    if (lane + 64 < n) {
        double d = (double)(lane + 64 - r), q = d / (2.0 * sd);
        v1 = exp(-q * q);
    }
    double part = v0 + v1;
    for (int m = 1; m < 64; m <<= 1) part += __shfl_xor(part, m);
    double inv = sgn / part;
    wl[lane] = v0 * inv;
    if (lane + 64 < 96) wl[lane + 64] = v1 * inv;
}

// ---- 1: horizontal blur + guard zeroing; 16 outputs/thread ----
// block 256 = 8 rows x 32 threads; grid (64 rowgroups, 14 planes), heavy first
__global__ __launch_bounds__(256) void hpass(const float* __restrict__ x,
                                             const float* __restrict__ sigma_list,
                                             float* __restrict__ h) {
    const int i = 13 - blockIdx.y;        // heavy plane first
    const int t = threadIdx.x;
    float s = sigma_list[i];
    int r = (int)(4.0f * s + 0.5f);
    int n = 2 * r + 1;
    int nceil = (n + 15) & ~15;

    __shared__ double wl[96];
    if (t < 64) make_w(s, +1.0, wl, t);

    // zero this block's share of the 86 guard rows (64 blocks x 688 = 86*512)
    {
        float* hp = h + i * (HROWS * 512);
        for (int k = t; k < 688; k += 256) {
            int f = blockIdx.x * 688 + k;      // 0..44031
            int g = f >> 9, xc = f & 511;      // g in 0..85
            int row = (g < HPAD) ? g : (g + 512);   // 0..42, 555..597
            hp[row * 512 + xc] = 0.0f;
        }
    }

    // stage 8 zero-padded rows, skewed (addr = p + p/16)
    __shared__ float rowp[8][648];
    int y8 = blockIdx.x * 8;
    for (int rr = 0; rr < 8; ++rr)
        for (int k = t; k < 608; k += 256) {
            int gx = k - 43;
            float val = ((unsigned)gx < 512u) ? x[(y8 + rr) * 512 + gx] : 0.0f;
            rowp[rr][k + (k >> 4)] = val;
        }
    __syncthreads();

    int tsub = t & 31, row = t >> 5;
    int xb = tsub * 16;
    int P0 = 43 - r + xb;
    double acc[16], win[16];
#pragma unroll
    for (int j = 0; j < 16; ++j) acc[j] = 0.0;
#pragma unroll
    for (int sl = 0; sl < 16; ++sl) {
        int p = P0 + sl;
        win[sl] = (double)rowp[row][p + (p >> 4)];
    }
    for (int dc = 0; dc < nceil; dc += 16) {
#pragma unroll
        for (int k = 0; k < 16; ++k) {
            double wd = wl[dc + k];
#pragma unroll
            for (int j = 0; j < 16; ++j)
                acc[j] = fma(wd, win[(k + j) & 15], acc[j]);
            int p = P0 + dc + k + 16;
            win[k] = (double)rowp[row][p + (p >> 4)];
        }
    }
    float* hp = h + (i * HROWS + HPAD + y8 + row) * 512 + xb;
#pragma unroll
    for (int j = 0; j < 16; ++j) hp[j] = (float)acc[j];
}

// Unconditional guarded conv: bp points at padded row (y0 - r + HPAD).
__device__ __forceinline__ void conv_acc(const float* __restrict__ bp,
                                         int nceil, const double* __restrict__ wl,
                                         double (&acc)[16]) {
    double win[16];
#pragma unroll
    for (int sl = 0; sl < 16; ++sl) win[sl] = (double)bp[sl * 512];
    for (int dc = 0; dc < nceil; dc += 16) {
        const float* rp = bp + (dc + 16) * 512;
#pragma unroll
        for (int k = 0; k < 16; ++k) {
            double wd = wl[dc + k];
#pragma unroll
            for (int j = 0; j < 16; ++j)
                acc[j] = fma(wd, win[(k + j) & 15], acc[j]);
            win[k] = (double)rp[k * 512];
        }
    }
}

// ---- 2: vertical blur pair + DoG; 1-wave blocks, heavy plane first ----
// grid (8 x-tiles, 32 y-tiles, 13 planes) = 3328 blocks of 64 threads
__global__ __launch_bounds__(64) void vdog(const float* __restrict__ h,
                                           const float* __restrict__ sigma_list,
                                           float* __restrict__ dog) {
    const int di = 12 - blockIdx.z;
    const int lane = threadIdx.x;
    const int x = blockIdx.x * 64 + lane;
    const int y0 = blockIdx.y * 16;
    float s0 = sigma_list[di], s1 = sigma_list[di + 1];
    int r0 = (int)(4.0f * s0 + 0.5f), n0 = 2 * r0 + 1, nc0 = (n0 + 15) & ~15;
    int r1 = (int)(4.0f * s1 + 0.5f), n1 = 2 * r1 + 1, nc1 = (n1 + 15) & ~15;
    __shared__ double wl0[96], wl1[96];
    make_w(s0, +1.0, wl0, lane);
    make_w(s1, -1.0, wl1, lane);          // negated: acc = conv0 - conv1
    __syncthreads();
    double acc[16];
#pragma unroll
    for (int j = 0; j < 16; ++j) acc[j] = 0.0;
    const float* hp0 = h + di * (HROWS * 512);
    conv_acc(hp0 + (HPAD + y0 - r0) * 512 + x, nc0, wl0, acc);
    const float* hp1 = hp0 + HROWS * 512;
    conv_acc(hp1 + (HPAD + y0 - r1) * 512 + x, nc1, wl1, acc);
    double sg = (double)s0;
    float* dp = dog + (di * 512 + y0) * 512 + x;
#pragma unroll
    for (int j = 0; j < 16; ++j) dp[j * 512] = (float)(acc[j] * sg);
}

// ---- 3: 3x3x3 peak detect; 8-row tile, colmax trick; group counts ----
// grid (64 y-tiles, 13 scales), block 512
__global__ __launch_bounds__(512) void detect(const float* __restrict__ dog,
                                              unsigned long long* __restrict__ rowbits,
                                              int* __restrict__ gcnt) {
    const int s = blockIdx.y;
    const int y0 = blockIdx.x * 8;
    const int group = s * 64 + blockIdx.x;
    const int t = threadIdx.x;
    const int w = t >> 6, lane = t & 63;

    if (s == 0 || s == 12) {
        if (t < 64) rowbits[(s * 512 + y0 + (t >> 3)) * 8 + (t & 7)] = 0ull;
        if (t == 0) gcnt[group] = 0;
        return;
    }

    float pm[10], vcen[8];
#pragma unroll
    for (int k = 0; k < 8; ++k) vcen[k] = 0.0f;
#pragma unroll
    for (int q = 0; q < 10; ++q) {
        int yy = y0 - 1 + q;
        float m = -3.0e38f;
        if ((unsigned)yy < 512u) {
            float a = dog[((s - 1) * 512 + yy) * 512 + t];
            float b = dog[(s * 512 + yy) * 512 + t];
            float c = dog[((s + 1) * 512 + yy) * 512 + t];
            m = fmaxf(a, fmaxf(b, c));
            if (q >= 1 && q <= 8) vcen[q - 1] = b;
        }
        pm[q] = m;
    }
    __shared__ float cml[8][512];
    __shared__ int cnt[8][8];
#pragma unroll
    for (int k = 0; k < 8; ++k)
        cml[k][t] = fmaxf(pm[k], fmaxf(pm[k + 1], pm[k + 2]));
    __syncthreads();
#pragma unroll
    for (int k = 0; k < 8; ++k) {
        int y = y0 + k;
        bool peak = false;
        if (t >= 1 && t <= 510 && y >= 1 && y <= 510) {
            float v = vcen[k];
            if (v > 0.001f) {
                float mx = fmaxf(cml[k][t - 1], fmaxf(cml[k][t], cml[k][t + 1]));
                peak = (v >= mx);          // mx includes v
            }
        }
        unsigned long long m = __ballot(peak);
        if (lane == 0) {
            rowbits[(s * 512 + y) * 8 + w] = m;
            cnt[k][w] = __popcll(m);
        }
    }
    __syncthreads();
    if (t == 0) {
        int c = 0;
#pragma unroll
        for (int k = 0; k < 8; ++k)
#pragma unroll
            for (int q = 0; q < 8; ++q) c += cnt[k][q];
        gcnt[group] = c;
    }
}

// ---- 4: ordered emit + padding fill; per-block redundant group reduce ----
// grid 832 blocks x 512 (block b covers scale b/64, rows (b%64)*8 .. +7)
__global__ __launch_bounds__(512) void emit(const unsigned long long* __restrict__ rowbits,
                                            const int* __restrict__ gcnt,
                                            const float* __restrict__ sigma_list,
                                            float* __restrict__ out) {
    const int b = blockIdx.x;
    const int s = b >> 6;
    const int y0 = (b & 63) * 8;
    const int t = threadIdx.x;
    const int lane = t & 63;

    __shared__ unsigned long long m[64];   // [row k][word q]
    __shared__ int pre[64];                // exclusive word prefix (row-major)
    __shared__ int redA[512], redB[512];

    if (t < 64) m[t] = rowbits[(s * 512 + y0 + (t >> 3)) * 8 + (t & 7)];

    int pa = 0, pb = 0;
    {
        int c0 = (t < 832) ? gcnt[t] : 0;
        int i1 = t + 512;
        int c1 = (i1 < 832) ? gcnt[i1] : 0;
        pb = c0 + c1;
        if (t < b) pa += c0;
        if (i1 < b) pa += c1;
    }
    redA[t] = pa;
    redB[t] = pb;
    __syncthreads();
    for (int off = 256; off > 0; off >>= 1) {
        if (t < off) { redA[t] += redA[t + off]; redB[t] += redB[t + off]; }
        __syncthreads();
    }
    int gbase = redA[0];
    int tot = min(redB[0], MAXPEAKS);

    if (t < 64) {                          // wave-0 exclusive scan of word counts
        int wc = (int)__popcll(m[t]);
        int inc = wc;
        for (int off = 1; off < 64; off <<= 1) {
            int v = __shfl_up(inc, off);
            if (lane >= off) inc += v;
        }
        pre[t] = inc - wc;
    }
    __syncthreads();

#pragma unroll
    for (int k = 0; k < 8; ++k) {
        int widx = k * 8 + (t >> 6);
        unsigned long long mw = m[widx];
        if ((mw >> lane) & 1ull) {
            int pos = gbase + pre[widx] + (int)__popcll(mw & ((1ull << lane) - 1ull));
            if (pos < MAXPEAKS) {
                out[pos * 3 + 0] = sigma_list[s];
                out[pos * 3 + 1] = (float)(y0 + k);
                out[pos * 3 + 2] = (float)t;
            }
        }
    }

    int idx = b * 512 + t;                 // blocks 0..63 cover all 32768 rows
    if (idx < MAXPEAKS && idx >= tot) {
        out[idx * 3 + 0] = sigma_list[0];
        out[idx * 3 + 1] = 0.0f;
        out[idx * 3 + 2] = 0.0f;
    }
}

extern "C" void kernel_launch(void* const* d_in, const int* in_sizes, int n_in,
                              void* d_out, int out_size, void* d_ws, size_t ws_size,
                              hipStream_t stream) {
    const float* x     = (const float*)d_in[0];   // [1,1,512,512]
    const float* sigma = (const float*)d_in[2];   // [14]
    float* out = (float*)d_out;                   // [32768,3]

    char* ws = (char*)d_ws;
    float* h                     = (float*)(ws + OFF_H);
    float* dog                   = (float*)(ws + OFF_DOG);
    unsigned long long* rowbits  = (unsigned long long*)(ws + OFF_BITS);
    int* gcnt                    = (int*)(ws + OFF_GCNT);

    hpass<<<dim3(64, 14), 256, 0, stream>>>(x, sigma, h);
    vdog<<<dim3(8, 32, 13), 64, 0, stream>>>(h, sigma, dog);
    detect<<<dim3(64, 13), 512, 0, stream>>>(dog, rowbits, gcnt);
    emit<<<832, 512, 0, stream>>>(rowbits, gcnt, sigma, out);
}